// Round 1
// baseline (2298.216 us; speedup 1.0000x reference)
//
#include <hip/hip_runtime.h>
#include <hip/hip_bf16.h>

// ---------------------------------------------------------------------------
// Hetero-GCN (3 node types, 9 relations), 2 GraphConv layers + classifier.
// Strategy: per relation, aggregate normalized src features via CSR gather
// (no float atomics), then dense GEMM [N,128]@[128,128] accumulated into the
// per-type hidden buffer. CSR built once per call, reused by both layers.
// All fp32.
// ---------------------------------------------------------------------------

#define NN 50000
#define EE 400000

// REL = [(0,2),(1,2),(1,0),(0,0),(2,1),(2,0),(0,0),(2,2),(1,1)]
__device__ __constant__ int d_rel_of_type[3][4] = {
    {2, 3, 5, 6},   // dst type 0
    {4, 8, -1, -1}, // dst type 1
    {0, 1, 7, -1},  // dst type 2
};

// ---------------- utility -------------------------------------------------
__global__ void k_zero_int(int* p, int n) {
    int i = blockIdx.x * blockDim.x + threadIdx.x;
    if (i < n) p[i] = 0;
}

// ---------------- degrees / norms -----------------------------------------
__global__ void k_degrees(const int* __restrict__ edges, int* __restrict__ deg_s,
                          int* __restrict__ deg_d) {
    int i = blockIdx.x * blockDim.x + threadIdx.x;
    if (i >= 9 * EE) return;
    int r = i / EE;
    int e = i - r * EE;
    int src = edges[(size_t)r * 2 * EE + e];
    int dst = edges[(size_t)r * 2 * EE + EE + e];
    atomicAdd(&deg_s[r * NN + src], 1);
    atomicAdd(&deg_d[r * NN + dst], 1);
}

__global__ void k_norms(const int* __restrict__ deg_s, const int* __restrict__ deg_d,
                        float* __restrict__ ns, float* __restrict__ nd) {
    int i = blockIdx.x * blockDim.x + threadIdx.x;
    if (i >= 9 * NN) return;
    int a = deg_s[i];
    int b = deg_d[i];
    ns[i] = (a > 0) ? rsqrtf((float)a) : 0.f;
    nd[i] = (b > 0) ? rsqrtf((float)b) : 0.f;
}

// ---------------- CSR build -----------------------------------------------
// one block per relation; exclusive scan of in-degree counts -> offsets
__global__ void k_scan(const int* __restrict__ counts, int* __restrict__ off,
                       int* __restrict__ cur) {
    __shared__ int sd[256];
    __shared__ int carry;
    int r = blockIdx.x;
    const int* c = counts + r * NN;
    int* o = off + r * (NN + 1);
    int* cu = cur + r * NN;
    int tid = threadIdx.x;
    if (tid == 0) carry = 0;
    __syncthreads();
    for (int base = 0; base < NN; base += 256) {
        int i = base + tid;
        int v = (i < NN) ? c[i] : 0;
        sd[tid] = v;
        __syncthreads();
        int x = v;
        for (int s = 1; s < 256; s <<= 1) {
            int t = (tid >= s) ? sd[tid - s] : 0;
            __syncthreads();
            x += t;
            sd[tid] = x;
            __syncthreads();
        }
        int excl = carry + x - v;
        if (i < NN) { o[i] = excl; cu[i] = excl; }
        __syncthreads();
        if (tid == 255) carry += x;
        __syncthreads();
    }
    if (tid == 0) o[NN] = carry;
}

__global__ void k_fill(const int* __restrict__ edges, int* __restrict__ cur,
                       int* __restrict__ esrc) {
    int i = blockIdx.x * blockDim.x + threadIdx.x;
    if (i >= 9 * EE) return;
    int r = i / EE;
    int e = i - r * EE;
    int src = edges[(size_t)r * 2 * EE + e];
    int dst = edges[(size_t)r * 2 * EE + EE + e];
    int pos = atomicAdd(&cur[r * NN + dst], 1);
    esrc[(size_t)r * EE + pos] = src;
}

// ---------------- bias init ------------------------------------------------
// H[t][n][c] = sum of b[r][c] over relations r with dst type t
__global__ void k_bias_init(const float* __restrict__ b, float* __restrict__ H) {
    int idx = blockIdx.x * blockDim.x + threadIdx.x; // float4 index into [3][NN][32]
    const int total = 3 * NN * 32;
    if (idx >= total) return;
    int t = idx / (NN * 32);
    int c4 = idx & 31;
    float4 s = make_float4(0.f, 0.f, 0.f, 0.f);
#pragma unroll
    for (int j = 0; j < 4; ++j) {
        int r = d_rel_of_type[t][j];
        if (r >= 0) {
            float4 bv = *reinterpret_cast<const float4*>(b + r * 128 + c4 * 4);
            s.x += bv.x; s.y += bv.y; s.z += bv.z; s.w += bv.w;
        }
    }
    *reinterpret_cast<float4*>((float*)H + (size_t)idx * 4) = s;
}

// ---------------- aggregation (CSR gather) ----------------------------------
// one wave per dst node; lane handles 2 cols (float2). A[d] = nd[d] * sum_e ns[s]*x[s]
template <int RELU>
__global__ __launch_bounds__(256) void k_agg(const float* __restrict__ xin,
                                             const int* __restrict__ off,
                                             const int* __restrict__ esrc,
                                             const float* __restrict__ ns,
                                             const float* __restrict__ nd,
                                             float* __restrict__ A) {
    int wave = (blockIdx.x * blockDim.x + threadIdx.x) >> 6;
    int lane = threadIdx.x & 63;
    if (wave >= NN) return;
    int d = wave;
    int e0 = off[d], e1 = off[d + 1];
    float a0 = 0.f, a1 = 0.f;
    for (int e = e0; e < e1; ++e) {
        int s = esrc[e];
        float w = ns[s];
        float2 v = *reinterpret_cast<const float2*>(xin + (size_t)s * 128 + lane * 2);
        float v0 = v.x, v1 = v.y;
        if (RELU) { v0 = fmaxf(v0, 0.f); v1 = fmaxf(v1, 0.f); }
        a0 += w * v0;
        a1 += w * v1;
    }
    float nrm = nd[d];
    float2 o = make_float2(a0 * nrm, a1 * nrm);
    *reinterpret_cast<float2*>(A + (size_t)d * 128 + lane * 2) = o;
}

// ---------------- GEMM: H += A @ W  (M=NN, K=128, N=128) --------------------
// block: 256 threads, tile 64 rows x 128 cols, thread micro-tile 4x8
__global__ __launch_bounds__(256) void k_gemm(const float* __restrict__ A,
                                              const float* __restrict__ W,
                                              float* __restrict__ H) {
    __shared__ float sA[32 * 68];   // [k][row], padded stride 68
    __shared__ float sW[32 * 128];  // [k][col]
    int tid = threadIdx.x;
    int row0 = blockIdx.x * 64;
    int tx = tid & 15;   // col group: cols tx*8 .. tx*8+7
    int ty = tid >> 4;   // row group: rows ty*4 .. ty*4+3
    float acc[4][8] = {};
    for (int k0 = 0; k0 < 128; k0 += 32) {
        __syncthreads();
        // stage A[row0..row0+63][k0..k0+31] transposed -> sA[k][row]
#pragma unroll
        for (int t = tid; t < 512; t += 256) {
            int rr = t >> 3;
            int kk = (t & 7) << 2;
            int grow = row0 + rr;
            float4 v = make_float4(0.f, 0.f, 0.f, 0.f);
            if (grow < NN)
                v = *reinterpret_cast<const float4*>(A + (size_t)grow * 128 + k0 + kk);
            sA[(kk + 0) * 68 + rr] = v.x;
            sA[(kk + 1) * 68 + rr] = v.y;
            sA[(kk + 2) * 68 + rr] = v.z;
            sA[(kk + 3) * 68 + rr] = v.w;
        }
        // stage W[k0..k0+31][0..127] -> sW
#pragma unroll
        for (int t = tid; t < 1024; t += 256) {
            *reinterpret_cast<float4*>(&sW[t * 4]) =
                *reinterpret_cast<const float4*>(W + (size_t)k0 * 128 + t * 4);
        }
        __syncthreads();
#pragma unroll
        for (int k = 0; k < 32; ++k) {
            float4 av = *reinterpret_cast<const float4*>(&sA[k * 68 + ty * 4]);
            float4 w0 = *reinterpret_cast<const float4*>(&sW[k * 128 + tx * 8]);
            float4 w1 = *reinterpret_cast<const float4*>(&sW[k * 128 + tx * 8 + 4]);
            float a[4] = {av.x, av.y, av.z, av.w};
            float w[8] = {w0.x, w0.y, w0.z, w0.w, w1.x, w1.y, w1.z, w1.w};
#pragma unroll
            for (int i = 0; i < 4; ++i)
#pragma unroll
                for (int j = 0; j < 8; ++j)
                    acc[i][j] = fmaf(a[i], w[j], acc[i][j]);
        }
    }
#pragma unroll
    for (int i = 0; i < 4; ++i) {
        int grow = row0 + ty * 4 + i;
        if (grow < NN) {
            float* hp = H + (size_t)grow * 128 + tx * 8;
            float4 h0 = *reinterpret_cast<float4*>(hp);
            float4 h1v = *reinterpret_cast<float4*>(hp + 4);
            h0.x += acc[i][0]; h0.y += acc[i][1]; h0.z += acc[i][2]; h0.w += acc[i][3];
            h1v.x += acc[i][4]; h1v.y += acc[i][5]; h1v.z += acc[i][6]; h1v.w += acc[i][7];
            *reinterpret_cast<float4*>(hp) = h0;
            *reinterpret_cast<float4*>(hp + 4) = h1v;
        }
    }
}

// ---------------- classifier: out = relu(H) @ Wc + bc -----------------------
__global__ __launch_bounds__(256) void k_classifier(const float* __restrict__ H,
                                                    const float* __restrict__ Wc,
                                                    const float* __restrict__ bc,
                                                    float* __restrict__ out) {
    __shared__ float sW[128 * 16];
    __shared__ float sb[16];
    int tid = threadIdx.x;
#pragma unroll
    for (int i = tid; i < 2048; i += 256) sW[i] = Wc[i];
    if (tid < 16) sb[tid] = bc[tid];
    __syncthreads();
    int node = blockIdx.x * 64 + (tid >> 2);
    if (node >= 3 * NN) return;
    int cg = (tid & 3) << 2;
    const float* h = H + (size_t)node * 128;
    float acc0 = 0.f, acc1 = 0.f, acc2 = 0.f, acc3 = 0.f;
#pragma unroll 4
    for (int k0 = 0; k0 < 128; k0 += 4) {
        float4 a4 = *reinterpret_cast<const float4*>(h + k0);
        float a;
        a = fmaxf(a4.x, 0.f);
        { float4 w = *reinterpret_cast<const float4*>(&sW[(k0 + 0) * 16 + cg]);
          acc0 = fmaf(a, w.x, acc0); acc1 = fmaf(a, w.y, acc1);
          acc2 = fmaf(a, w.z, acc2); acc3 = fmaf(a, w.w, acc3); }
        a = fmaxf(a4.y, 0.f);
        { float4 w = *reinterpret_cast<const float4*>(&sW[(k0 + 1) * 16 + cg]);
          acc0 = fmaf(a, w.x, acc0); acc1 = fmaf(a, w.y, acc1);
          acc2 = fmaf(a, w.z, acc2); acc3 = fmaf(a, w.w, acc3); }
        a = fmaxf(a4.z, 0.f);
        { float4 w = *reinterpret_cast<const float4*>(&sW[(k0 + 2) * 16 + cg]);
          acc0 = fmaf(a, w.x, acc0); acc1 = fmaf(a, w.y, acc1);
          acc2 = fmaf(a, w.z, acc2); acc3 = fmaf(a, w.w, acc3); }
        a = fmaxf(a4.w, 0.f);
        { float4 w = *reinterpret_cast<const float4*>(&sW[(k0 + 3) * 16 + cg]);
          acc0 = fmaf(a, w.x, acc0); acc1 = fmaf(a, w.y, acc1);
          acc2 = fmaf(a, w.z, acc2); acc3 = fmaf(a, w.w, acc3); }
    }
    float4 o = make_float4(acc0 + sb[cg], acc1 + sb[cg + 1],
                           acc2 + sb[cg + 2], acc3 + sb[cg + 3]);
    *reinterpret_cast<float4*>(out + (size_t)node * 16 + cg) = o;
}

// ---------------------------------------------------------------------------
extern "C" void kernel_launch(void* const* d_in, const int* in_sizes, int n_in,
                              void* d_out, int out_size, void* d_ws, size_t ws_size,
                              hipStream_t stream) {
    const float* x0 = (const float*)d_in[0];
    const float* x1 = (const float*)d_in[1];
    const float* x2 = (const float*)d_in[2];
    const float* W1 = (const float*)d_in[3];
    const float* b1 = (const float*)d_in[4];
    const float* W2 = (const float*)d_in[5];
    const float* b2 = (const float*)d_in[6];
    const float* Wc = (const float*)d_in[7];
    const float* bc = (const float*)d_in[8];
    const int* edges = (const int*)d_in[9];
    const float* x[3] = {x0, x1, x2};

    // REL src/dst tables
    const int REL_S[9] = {0, 1, 1, 0, 2, 2, 0, 2, 1};
    const int REL_D[9] = {2, 2, 0, 0, 1, 0, 0, 2, 1};

    // workspace carve-up (~205 MB)
    char* p = (char*)d_ws;
    auto alloc = [&](size_t bytes) -> void* {
        void* r = (void*)p;
        p += (bytes + 255) & ~(size_t)255;
        return r;
    };
    int*   deg  = (int*)  alloc((size_t)2 * 9 * NN * sizeof(int)); // deg_s | deg_d
    float* ns   = (float*)alloc((size_t)9 * NN * sizeof(float));
    float* nd   = (float*)alloc((size_t)9 * NN * sizeof(float));
    int*   off  = (int*)  alloc((size_t)9 * (NN + 1) * sizeof(int));
    int*   cur  = (int*)  alloc((size_t)9 * NN * sizeof(int));
    int*   esrc = (int*)  alloc((size_t)9 * EE * sizeof(int));
    float* Abuf = (float*)alloc((size_t)NN * 128 * sizeof(float));
    float* h1   = (float*)alloc((size_t)3 * NN * 128 * sizeof(float));
    float* h2   = (float*)alloc((size_t)3 * NN * 128 * sizeof(float));
    int* deg_s = deg;
    int* deg_d = deg + 9 * NN;

    // ---- degrees, norms, CSR (reused by both layers) ----
    k_zero_int<<<(2 * 9 * NN + 255) / 256, 256, 0, stream>>>(deg, 2 * 9 * NN);
    k_degrees<<<(9 * EE + 255) / 256, 256, 0, stream>>>(edges, deg_s, deg_d);
    k_norms<<<(9 * NN + 255) / 256, 256, 0, stream>>>(deg_s, deg_d, ns, nd);
    k_scan<<<9, 256, 0, stream>>>(deg_d, off, cur);
    k_fill<<<(9 * EE + 255) / 256, 256, 0, stream>>>(edges, cur, esrc);

    const int agg_blocks = (NN * 64) / 256;       // 12500
    const int gemm_blocks = (NN + 63) / 64;       // 782
    const int bias_blocks = (3 * NN * 32) / 256;  // 18750

    // ---- layer 1 ----
    k_bias_init<<<bias_blocks, 256, 0, stream>>>(b1, h1);
    for (int r = 0; r < 9; ++r) {
        int s = REL_S[r], d = REL_D[r];
        k_agg<0><<<agg_blocks, 256, 0, stream>>>(x[s], off + r * (NN + 1),
                                                 esrc + (size_t)r * EE,
                                                 ns + r * NN, nd + r * NN, Abuf);
        k_gemm<<<gemm_blocks, 256, 0, stream>>>(Abuf, W1 + (size_t)r * 128 * 128,
                                                h1 + (size_t)d * NN * 128);
    }

    // ---- layer 2 (input = relu(h1), folded into gather) ----
    k_bias_init<<<bias_blocks, 256, 0, stream>>>(b2, h2);
    for (int r = 0; r < 9; ++r) {
        int s = REL_S[r], d = REL_D[r];
        k_agg<1><<<agg_blocks, 256, 0, stream>>>(h1 + (size_t)s * NN * 128,
                                                 off + r * (NN + 1),
                                                 esrc + (size_t)r * EE,
                                                 ns + r * NN, nd + r * NN, Abuf);
        k_gemm<<<gemm_blocks, 256, 0, stream>>>(Abuf, W2 + (size_t)r * 128 * 128,
                                                h2 + (size_t)d * NN * 128);
    }

    // ---- classifier: out = relu(h2) @ Wc + bc ----
    k_classifier<<<(3 * NN + 63) / 64, 256, 0, stream>>>(h2, Wc, bc, (float*)d_out);
}